// Round 2
// baseline (846.437 us; speedup 1.0000x reference)
//
#include <hip/hip_runtime.h>
#include <math.h>

#define N_Q 20000
#define KK 48
#define CC 64
#define FFD 256
#define OUTD 64

// ---------------------------------------------------------------------------
// Transpose all weight matrices into ws so per-thread row reads are coalesced.
// Layout in tw (floats):
//   [0,4096)      WqT  [j*64+r]  = Wq[r,j]      (in_w rows 0..63)
//   [4096,8192)   WkT                            (in_w rows 64..127)
//   [8192,12288)  WvT                            (in_w rows 128..191)
//   [12288,16384) WoT  [j*64+r]  = out_w[r,j]
//   [16384,32768) L1T  [j*256+f] = lin1_w[f,j]
//   [32768,49152) L2T  [f*64+c]  = lin2_w[c,f]
//   [49152,53248) OlT  [j*64+o]  = outl_w[o,j]
// ---------------------------------------------------------------------------
__global__ void transpose_weights(const float* __restrict__ in_w,
                                  const float* __restrict__ out_w,
                                  const float* __restrict__ lin1_w,
                                  const float* __restrict__ lin2_w,
                                  const float* __restrict__ outl_w,
                                  float* __restrict__ tw)
{
    int t = blockIdx.x * blockDim.x + threadIdx.x;
    if (t < 12288) {
        int sub = t >> 12, rem = t & 4095, r = rem >> 6, j = rem & 63;
        tw[(sub << 12) + j * 64 + r] = in_w[t];
    } else if (t < 16384) {
        int idx = t - 12288, r = idx >> 6, j = idx & 63;
        tw[12288 + j * 64 + r] = out_w[idx];
    } else if (t < 32768) {
        int idx = t - 16384, r = idx >> 6, j = idx & 63;   // 256 rows, 64 cols
        tw[16384 + j * 256 + r] = lin1_w[idx];
    } else if (t < 49152) {
        int idx = t - 32768, r = idx >> 8, jf = idx & 255; // 64 rows, 256 cols
        tw[32768 + jf * 64 + r] = lin2_w[idx];
    } else if (t < 53248) {
        int idx = t - 49152, r = idx >> 6, j = idx & 63;
        tw[49152 + j * 64 + r] = outl_w[idx];
    }
}

// async global->LDS: each lane contributes 16B; LDS dest = base + lane*16
__device__ __forceinline__ void async_load16(const float* g, float* l)
{
    __builtin_amdgcn_global_load_lds(
        (const __attribute__((address_space(1))) void*)g,
        (__attribute__((address_space(3))) void*)l, 16, 0, 0);
}

// ---------------------------------------------------------------------------
// One wave per query. Thread = channel c. Two passes (K then V) so only 64
// weight VGPRs are live at a time. Single wave => LDS ops are in program
// order; no barriers needed except after the async staging.
// ---------------------------------------------------------------------------
__global__ __launch_bounds__(64, 1) void attn_kernel(
    const float* __restrict__ vfeat,
    const float* __restrict__ vcoord,
    const float* __restrict__ qcoord,
    const int*   __restrict__ kidx,
    const float* __restrict__ q_w,
    const float* __restrict__ q_b,
    const float* __restrict__ kpos_w,
    const float* __restrict__ kpos_b,
    const float* __restrict__ in_b,
    const float* __restrict__ out_b,
    const float* __restrict__ lin1_b,
    const float* __restrict__ lin2_b,
    const float* __restrict__ tw,
    float* __restrict__ y_out,
    float* __restrict__ sum1,
    float* __restrict__ sumsq1)
{
    const int n = blockIdx.x;
    const int c = threadIdx.x;
    const int h = c >> 4;
    const int l = c & 15;

    const float* WqT = tw;
    const float* WkT = tw + 4096;
    const float* WvT = tw + 8192;
    const float* WoT = tw + 12288;
    const float* L1T = tw + 16384;
    const float* L2T = tw + 32768;

    __shared__ __align__(16) float sh_kf[KK * CC];   // 12288 B, reused later
    __shared__ __align__(16) float sh_sc[4 * KK];    // 768 B
    __shared__ __align__(16) float sh_qf[CC];        // 256 B
    float* sh_ctx = sh_kf;            // aliases: kf dead after V-pass
    float* sh_att = sh_kf + 64;
    float* sh_hid = sh_kf + 128;      // 256 floats

    const float qc0 = qcoord[n * 3 + 0];
    const float qc1 = qcoord[n * 3 + 1];
    const float qc2 = qcoord[n * 3 + 2];

    // ---- stage all 48 key feature rows into LDS (async, 12 x 1KB) ----
    {
        const int r4 = c >> 4, col = (c & 15) << 2;   // lane -> (row-of-4, 4-float col)
        #pragma unroll
        for (int kb = 0; kb < KK / 4; ++kb) {
            int k = kb * 4 + r4;
            int idx = kidx[n * KK + k];
            int safe = idx < 0 ? 0 : idx;
            async_load16(vfeat + (size_t)safe * CC + col, &sh_kf[kb * 4 * CC]);
        }
    }

    // ---- query positional projection (overlaps staging latency) ----
    float qf = fmaf(q_w[c * 3 + 2], qc2, q_b[c]);
    qf = fmaf(q_w[c * 3 + 1], qc1, qf);
    qf = fmaf(q_w[c * 3 + 0], qc0, qf);
    sh_qf[c] = fmaxf(qf, 0.0f);

    // q = (Wq @ q_feat + bq) / 4   (sh_qf RAW is same-wave => in-order safe)
    float qreg = in_b[c];
    #pragma unroll
    for (int j = 0; j < CC; ++j)
        qreg = fmaf(sh_qf[j], WqT[j * 64 + c], qreg);
    qreg *= 0.25f;

    const float kw0 = kpos_w[c * 3 + 0], kw1 = kpos_w[c * 3 + 1],
                kw2 = kpos_w[c * 3 + 2], kpb = kpos_b[c];

    // K weights into registers (64 VGPRs, coalesced)
    float wk[CC];
    #pragma unroll
    for (int j = 0; j < CC; ++j) wk[j] = WkT[j * 64 + c];
    const float bk = in_b[64 + c];

    __builtin_amdgcn_s_waitcnt(0);   // drain async staging
    __syncthreads();

    // ---- add positional encoding in-place (coords are wave-uniform) ----
    for (int k = 0; k < KK; ++k) {
        int idx = kidx[n * KK + k];
        int safe = idx < 0 ? 0 : idx;
        float r0 = vcoord[safe * 3 + 0] - qc0;
        float r1 = vcoord[safe * 3 + 1] - qc1;
        float r2 = vcoord[safe * 3 + 2] - qc2;
        float pe = fmaf(kw2, r2, kpb);
        pe = fmaf(kw1, r1, pe);
        pe = fmaf(kw0, r0, pe);
        sh_kf[k * CC + c] += fmaxf(pe, 0.0f);
    }

    // ---- pass K: scores ----
    for (int k = 0; k < KK; ++k) {
        float aK0 = bk, aK1 = 0.0f;
        #pragma unroll
        for (int j = 0; j < CC; j += 8) {
            float4 a = *(const float4*)&sh_kf[k * CC + j];
            float4 b = *(const float4*)&sh_kf[k * CC + j + 4];
            aK0 = fmaf(a.x, wk[j + 0], aK0);
            aK0 = fmaf(a.y, wk[j + 1], aK0);
            aK0 = fmaf(a.z, wk[j + 2], aK0);
            aK0 = fmaf(a.w, wk[j + 3], aK0);
            aK1 = fmaf(b.x, wk[j + 4], aK1);
            aK1 = fmaf(b.y, wk[j + 5], aK1);
            aK1 = fmaf(b.z, wk[j + 6], aK1);
            aK1 = fmaf(b.w, wk[j + 7], aK1);
        }
        float p = qreg * (aK0 + aK1);
        #pragma unroll
        for (int off = 8; off >= 1; off >>= 1) p += __shfl_xor(p, off, 16);
        int idx = kidx[n * KK + k];           // uniform (scalar load)
        if (l == 0) sh_sc[h * KK + k] = (idx < 0) ? -INFINITY : p;
    }

    // ---- softmax (lane l of head h handles k = l, l+16, l+32) ----
    {
        float s0 = sh_sc[h * KK + l], s1 = sh_sc[h * KK + l + 16], s2 = sh_sc[h * KK + l + 32];
        float mx = fmaxf(s0, fmaxf(s1, s2));
        #pragma unroll
        for (int off = 8; off >= 1; off >>= 1) mx = fmaxf(mx, __shfl_xor(mx, off, 16));
        float e0 = __expf(s0 - mx), e1 = __expf(s1 - mx), e2 = __expf(s2 - mx);
        float es = e0 + e1 + e2;
        #pragma unroll
        for (int off = 8; off >= 1; off >>= 1) es += __shfl_xor(es, off, 16);
        float r = 1.0f / es;
        sh_sc[h * KK + l]      = e0 * r;
        sh_sc[h * KK + l + 16] = e1 * r;
        sh_sc[h * KK + l + 32] = e2 * r;
    }

    // ---- pass V: V projection fused with ctx accumulation ----
    float wv[CC];
    #pragma unroll
    for (int j = 0; j < CC; ++j) wv[j] = WvT[j * 64 + c];
    const float bv = in_b[128 + c];

    float ctx = 0.0f;
    for (int k = 0; k < KK; ++k) {
        float aV0 = bv, aV1 = 0.0f;
        #pragma unroll
        for (int j = 0; j < CC; j += 8) {
            float4 a = *(const float4*)&sh_kf[k * CC + j];
            float4 b = *(const float4*)&sh_kf[k * CC + j + 4];
            aV0 = fmaf(a.x, wv[j + 0], aV0);
            aV0 = fmaf(a.y, wv[j + 1], aV0);
            aV0 = fmaf(a.z, wv[j + 2], aV0);
            aV0 = fmaf(a.w, wv[j + 3], aV0);
            aV1 = fmaf(b.x, wv[j + 4], aV1);
            aV1 = fmaf(b.y, wv[j + 5], aV1);
            aV1 = fmaf(b.z, wv[j + 6], aV1);
            aV1 = fmaf(b.w, wv[j + 7], aV1);
        }
        ctx = fmaf(sh_sc[h * KK + k], aV0 + aV1, ctx);
    }
    sh_ctx[c] = ctx;   // aliases sh_kf[0..63] — kf fully consumed above (in-order)

    // ---- output projection ----
    float att = out_b[c];
    #pragma unroll 8
    for (int j = 0; j < CC; ++j)
        att = fmaf(sh_ctx[j], WoT[j * 64 + c], att);
    sh_att[c] = att;

    // ---- FFN: thread c computes hidden f = c, c+64, c+128, c+192 ----
    float h0 = lin1_b[c], h1 = lin1_b[c + 64], h2 = lin1_b[c + 128], h3 = lin1_b[c + 192];
    #pragma unroll 8
    for (int j = 0; j < CC; ++j) {
        float a = sh_att[j];
        h0 = fmaf(a, L1T[j * 256 + c + 0  ], h0);
        h1 = fmaf(a, L1T[j * 256 + c + 64 ], h1);
        h2 = fmaf(a, L1T[j * 256 + c + 128], h2);
        h3 = fmaf(a, L1T[j * 256 + c + 192], h3);
    }
    sh_hid[c + 0  ] = fmaxf(h0, 0.0f);
    sh_hid[c + 64 ] = fmaxf(h1, 0.0f);
    sh_hid[c + 128] = fmaxf(h2, 0.0f);
    sh_hid[c + 192] = fmaxf(h3, 0.0f);

    float y = att + lin2_b[c];
    #pragma unroll 16
    for (int ff = 0; ff < FFD; ++ff)
        y = fmaf(sh_hid[ff], L2T[ff * 64 + c], y);

    y_out[n * 64 + c] = y;
    atomicAdd(&sum1[c], y);
    atomicAdd(&sumsq1[c], y * y);
}

// ---------------------------------------------------------------------------
// Fold BN stats into scale/shift: a = g*rsqrt(var+eps), b' = b - mu*a
// ---------------------------------------------------------------------------
__global__ void bn_stats_kernel(const float* __restrict__ sum,
                                const float* __restrict__ sumsq,
                                const float* __restrict__ g,
                                const float* __restrict__ b,
                                float* __restrict__ a_out,
                                float* __restrict__ b_out)
{
    int c = threadIdx.x;
    const float invN = 1.0f / 20000.0f;
    float mu  = sum[c] * invN;
    float var = fmaf(-mu, mu, sumsq[c] * invN);
    float inv = 1.0f / sqrtf(var + 1e-5f);
    float a = g[c] * inv;
    a_out[c] = a;
    b_out[c] = fmaf(-mu, a, b[c]);
}

// ---------------------------------------------------------------------------
// xn = y*a1+b1 ; z = OutL @ xn + b ; accumulate BN2 stats. 16 rows per block.
// Single wave per block: no barriers (LDS in-order within a wave).
// ---------------------------------------------------------------------------
#define LO_ROWS 16
__global__ __launch_bounds__(64, 1) void lin_out_kernel(
    const float* __restrict__ y,
    const float* __restrict__ a1,
    const float* __restrict__ b1,
    const float* __restrict__ outlT,
    const float* __restrict__ outl_b,
    float* __restrict__ z,
    float* __restrict__ sum2,
    float* __restrict__ sumsq2)
{
    int c = threadIdx.x;
    __shared__ __align__(16) float sh_xn[CC];
    float w[CC];
    #pragma unroll
    for (int j = 0; j < CC; ++j) w[j] = outlT[j * 64 + c];
    float ob = outl_b[c];
    float ac = a1[c], bc = b1[c];
    float s = 0.0f, ss = 0.0f;
    int base = blockIdx.x * LO_ROWS;
    for (int r = 0; r < LO_ROWS; ++r) {
        int n = base + r;
        float yv = y[n * 64 + c];
        sh_xn[c] = fmaf(yv, ac, bc);     // write r issued after reads r-1 (in-order)
        float acc = ob;
        #pragma unroll
        for (int j = 0; j < CC; j += 4) {
            float4 x4 = *(const float4*)&sh_xn[j];
            acc = fmaf(x4.x, w[j + 0], acc);
            acc = fmaf(x4.y, w[j + 1], acc);
            acc = fmaf(x4.z, w[j + 2], acc);
            acc = fmaf(x4.w, w[j + 3], acc);
        }
        z[n * 64 + c] = acc;
        s += acc;
        ss += acc * acc;
    }
    atomicAdd(&sum2[c], s);
    atomicAdd(&sumsq2[c], ss);
}

// ---------------------------------------------------------------------------
// out = relu(z*a2 + b2), in place on d_out, float4 vectorized
// ---------------------------------------------------------------------------
__global__ void final_kernel(float* __restrict__ z,
                             const float* __restrict__ a2,
                             const float* __restrict__ b2)
{
    int i = blockIdx.x * blockDim.x + threadIdx.x;
    if (i < N_Q * OUTD / 4) {
        float4 v = ((float4*)z)[i];
        int o = (i << 2) & 63;
        v.x = fmaxf(fmaf(v.x, a2[o + 0], b2[o + 0]), 0.0f);
        v.y = fmaxf(fmaf(v.y, a2[o + 1], b2[o + 1]), 0.0f);
        v.z = fmaxf(fmaf(v.z, a2[o + 2], b2[o + 2]), 0.0f);
        v.w = fmaxf(fmaf(v.w, a2[o + 3], b2[o + 3]), 0.0f);
        ((float4*)z)[i] = v;
    }
}

extern "C" void kernel_launch(void* const* d_in, const int* in_sizes, int n_in,
                              void* d_out, int out_size, void* d_ws, size_t ws_size,
                              hipStream_t stream)
{
    const float* vfeat  = (const float*)d_in[0];
    const float* vcoord = (const float*)d_in[1];
    const float* qcoord = (const float*)d_in[2];
    const int*   kidx   = (const int*)d_in[3];
    const float* q_w    = (const float*)d_in[4];
    const float* q_b    = (const float*)d_in[5];
    const float* kpos_w = (const float*)d_in[6];
    const float* kpos_b = (const float*)d_in[7];
    const float* in_w   = (const float*)d_in[8];
    const float* in_b   = (const float*)d_in[9];
    const float* out_w  = (const float*)d_in[10];
    const float* out_b  = (const float*)d_in[11];
    const float* lin1_w = (const float*)d_in[12];
    const float* lin1_b = (const float*)d_in[13];
    const float* lin2_w = (const float*)d_in[14];
    const float* lin2_b = (const float*)d_in[15];
    const float* norm_g = (const float*)d_in[16];
    const float* norm_b = (const float*)d_in[17];
    const float* outl_w = (const float*)d_in[18];
    const float* outl_b = (const float*)d_in[19];
    const float* obn_g  = (const float*)d_in[20];
    const float* obn_b  = (const float*)d_in[21];

    float* ws     = (float*)d_ws;
    float* y      = ws;                 // N*64 = 1,280,000 floats
    float* stats  = ws + 1280000;       // 512 floats
    float* tw     = ws + 1280512;       // 53,248 floats
    float* sum1   = stats;
    float* sumsq1 = stats + 64;
    float* a1     = stats + 128;
    float* b1     = stats + 192;
    float* sum2   = stats + 256;
    float* sumsq2 = stats + 320;
    float* a2     = stats + 384;
    float* b2     = stats + 448;
    float* z      = (float*)d_out;

    hipMemsetAsync(stats, 0, 512 * sizeof(float), stream);
    transpose_weights<<<208, 256, 0, stream>>>(in_w, out_w, lin1_w, lin2_w, outl_w, tw);
    attn_kernel<<<N_Q, 64, 0, stream>>>(vfeat, vcoord, qcoord, kidx, q_w, q_b,
                                        kpos_w, kpos_b, in_b, out_b, lin1_b, lin2_b,
                                        tw, y, sum1, sumsq1);
    bn_stats_kernel<<<1, 64, 0, stream>>>(sum1, sumsq1, norm_g, norm_b, a1, b1);
    lin_out_kernel<<<N_Q / LO_ROWS, 64, 0, stream>>>(y, a1, b1, tw + 49152, outl_b, z, sum2, sumsq2);
    bn_stats_kernel<<<1, 64, 0, stream>>>(sum2, sumsq2, obn_g, obn_b, a2, b2);
    final_kernel<<<1250, 256, 0, stream>>>(z, a2, b2);
}

// Round 3
// 394.605 us; speedup vs baseline: 2.1450x; 2.1450x over previous
//
#include <hip/hip_runtime.h>
#include <hip/hip_bf16.h>
#include <math.h>

#define N_Q 20000
#define KK 48
#define CC 64
#define FFD 256

// ws float offsets
#define TW_WOT   0        // 4096:  WoT[j*64+c]      = out_w[c*64+j]
#define TW_WVT   4096     // 4096:  WvT[cp*64+c]     = in_w[(128+c)*64+cp]  (Wv[c,cp])
#define TW_L1I   8192     // 16384: L1I[j*256+f]     = lin1_w[f*64+j]
#define TW_L2I   24576    // 16384: L2I[f4*256+4c+m] = lin2_w[c*256+4*f4+m]
#define TW_OLT   40960    // 4096:  OlT[j*64+o]      = outl_w[o*64+j]
#define TW_SIZE  45056
#define ST_OFF   45056    // 256 floats: sum1,sumsq1,sum2,sumsq2
#define M_OFF    45568    // bf16 M_all[n][j*4+h], 20000*256 ushorts

// ---------------------------------------------------------------------------
__global__ void prep_weights(const float* __restrict__ in_w,
                             const float* __restrict__ out_w,
                             const float* __restrict__ lin1_w,
                             const float* __restrict__ lin2_w,
                             const float* __restrict__ outl_w,
                             float* __restrict__ tw)
{
    int t = blockIdx.x * 256 + threadIdx.x;
    if (t < 4096) {
        int c = t >> 6, j = t & 63;
        tw[TW_WOT + j*64 + c] = out_w[c*64 + j];
    } else if (t < 8192) {
        int i = t - 4096, cp = i >> 6, c = i & 63;
        tw[TW_WVT + cp*64 + c] = in_w[(128 + c)*64 + cp];
    } else if (t < 24576) {
        int i = t - 8192, f = i >> 6, j = i & 63;
        tw[TW_L1I + j*256 + f] = lin1_w[f*64 + j];
    } else if (t < 40960) {
        int i = t - 24576, c = i >> 8, fm = i & 255;
        tw[TW_L2I + (fm >> 2)*256 + 4*c + (fm & 3)] = lin2_w[c*256 + fm];
    } else if (t < 45056) {
        int i = t - 40960, o = i >> 6, j = i & 63;
        tw[TW_OLT + j*64 + o] = outl_w[o*64 + j];
    }
}

// ---------------------------------------------------------------------------
// M_all[n][j,h] = sum_d q[n,h*16+d] * Wk[h*16+d, j]; q = (Wq@relu(qw@qc+qb)+bq)/4
// Dense over queries: Wq/Wk read once per block (LDS), 32 queries/block.
// ---------------------------------------------------------------------------
__global__ __launch_bounds__(256) void m_kernel(
    const float* __restrict__ qcoord, const float* __restrict__ q_w,
    const float* __restrict__ q_b, const float* __restrict__ in_w,
    const float* __restrict__ in_b, __hip_bfloat16* __restrict__ M_all)
{
    __shared__ float sWq[64*65];   // Wq[c][j] pad65: bank (c+j)%32 conflict-free
    __shared__ float sWk[64*65];
    __shared__ float sqf[4][64];
    __shared__ float sq[4][64];
    int tid = threadIdx.x;
    for (int i = tid; i < 8192; i += 256) {
        int r = i >> 6, j = i & 63;
        float v = in_w[i];                     // rows 0..63 = Wq, 64..127 = Wk
        if (r < 64) sWq[r*65 + j] = v; else sWk[(r - 64)*65 + j] = v;
    }
    __syncthreads();
    int w = tid >> 6, c = tid & 63;
    int j_lo = c & 15, h = c >> 4;
    float qw0 = q_w[c*3+0], qw1 = q_w[c*3+1], qw2 = q_w[c*3+2];
    float qb = q_b[c], bq = in_b[c];
    for (int qi = 0; qi < 8; ++qi) {
        int n = blockIdx.x*32 + w*8 + qi;
        float qc0 = qcoord[n*3+0], qc1 = qcoord[n*3+1], qc2 = qcoord[n*3+2];
        float qf = fmaf(qw2, qc2, qb); qf = fmaf(qw1, qc1, qf); qf = fmaf(qw0, qc0, qf);
        sqf[w][c] = fmaxf(qf, 0.0f);           // single wave: in-order LDS
        float q = bq;
        #pragma unroll 8
        for (int j = 0; j < 64; ++j) q = fmaf(sqf[w][j], sWq[c*65 + j], q);
        q *= 0.25f;
        sq[w][c] = q;
        float m0 = 0, m1 = 0, m2 = 0, m3 = 0;
        #pragma unroll
        for (int d = 0; d < 16; ++d) {
            float qv = sq[w][h*16 + d];
            const float* wr = &sWk[(h*16 + d)*65];
            m0 = fmaf(qv, wr[j_lo],      m0);
            m1 = fmaf(qv, wr[j_lo + 16], m1);
            m2 = fmaf(qv, wr[j_lo + 32], m2);
            m3 = fmaf(qv, wr[j_lo + 48], m3);
        }
        __hip_bfloat16* Mp = M_all + (size_t)n*256;
        Mp[ j_lo       *4 + h] = __float2bfloat16(m0);
        Mp[(j_lo + 16) *4 + h] = __float2bfloat16(m1);
        Mp[(j_lo + 32) *4 + h] = __float2bfloat16(m2);
        Mp[(j_lo + 48) *4 + h] = __float2bfloat16(m3);
    }
}

// ---------------------------------------------------------------------------
// One wave per query. S = KF@M, softmax, T = P@KF, ctx = T@WvT + bv,
// att = WoT'ctx + bo. Barrier-free (single wave).
// ---------------------------------------------------------------------------
__global__ __launch_bounds__(64) void attn_kernel(
    const float* __restrict__ vfeat, const float* __restrict__ vcoord,
    const float* __restrict__ qcoord, const int* __restrict__ kidx,
    const float* __restrict__ kpos_w, const float* __restrict__ kpos_b,
    const float* __restrict__ in_b, const float* __restrict__ out_b,
    const float* __restrict__ tw, const __hip_bfloat16* __restrict__ M_all,
    float* __restrict__ att_out)
{
    __shared__ __align__(16) float skf[KK*68];   // pad 68: b128 row reads 2-way max
    __shared__ __align__(16) float sM[256];      // [j*4+h]
    __shared__ __align__(16) float sP[KK*4];     // [k*4+h]
    __shared__ __align__(16) float sT[4*68];
    __shared__ __align__(16) float sctx[64];
    int n = blockIdx.x, c = threadIdx.x;
    int l = c & 15, h = c >> 4;

    // stage M (bf16 -> f32)
    {
        uint2 mu = ((const uint2*)(M_all + (size_t)n*256))[c];
        float4 mf;
        mf.x = __uint_as_float(mu.x << 16);
        mf.y = __uint_as_float(mu.x & 0xffff0000u);
        mf.z = __uint_as_float(mu.y << 16);
        mf.w = __uint_as_float(mu.y & 0xffff0000u);
        *(float4*)&sM[4*c] = mf;
    }

    float qc0 = qcoord[n*3+0], qc1 = qcoord[n*3+1], qc2 = qcoord[n*3+2];
    float kw0 = kpos_w[c*3+0], kw1 = kpos_w[c*3+1], kw2 = kpos_w[c*3+2];
    float kpb = kpos_b[c];
    const int* kr = kidx + n*KK;

    // gather + positional encoding
    #pragma unroll 8
    for (int k = 0; k < KK; ++k) {
        int idx = kr[k];                          // wave-uniform (scalar)
        int safe = idx < 0 ? 0 : idx;
        float f = vfeat[(size_t)safe*64 + c];
        float r0 = vcoord[safe*3+0] - qc0;
        float r1 = vcoord[safe*3+1] - qc1;
        float r2 = vcoord[safe*3+2] - qc2;
        float pe = fmaf(kw2, r2, kpb); pe = fmaf(kw1, r1, pe); pe = fmaf(kw0, r0, pe);
        skf[k*68 + c] = f + fmaxf(pe, 0.0f);
    }

    // scores: lane (l,h) computes S[h, l], S[h, l+16], S[h, l+32]
    int i0 = kr[l], i1 = kr[l + 16], i2 = kr[l + 32];
    float S0 = 0, S1 = 0, S2 = 0;
    #pragma unroll
    for (int j4 = 0; j4 < 16; ++j4) {
        float4 a = *(const float4*)&skf[ l       *68 + 4*j4];
        float4 b = *(const float4*)&skf[(l + 16) *68 + 4*j4];
        float4 d = *(const float4*)&skf[(l + 32) *68 + 4*j4];
        float m0 = sM[(4*j4 + 0)*4 + h], m1 = sM[(4*j4 + 1)*4 + h];
        float m2 = sM[(4*j4 + 2)*4 + h], m3 = sM[(4*j4 + 3)*4 + h];
        S0 = fmaf(a.x, m0, S0); S0 = fmaf(a.y, m1, S0); S0 = fmaf(a.z, m2, S0); S0 = fmaf(a.w, m3, S0);
        S1 = fmaf(b.x, m0, S1); S1 = fmaf(b.y, m1, S1); S1 = fmaf(b.z, m2, S1); S1 = fmaf(b.w, m3, S1);
        S2 = fmaf(d.x, m0, S2); S2 = fmaf(d.y, m1, S2); S2 = fmaf(d.z, m2, S2); S2 = fmaf(d.w, m3, S2);
    }
    if (i0 < 0) S0 = -INFINITY;
    if (i1 < 0) S1 = -INFINITY;
    if (i2 < 0) S2 = -INFINITY;

    // softmax across the 16 lanes of head h
    float mx = fmaxf(S0, fmaxf(S1, S2));
    #pragma unroll
    for (int off = 8; off >= 1; off >>= 1) mx = fmaxf(mx, __shfl_xor(mx, off, 16));
    float e0 = __expf(S0 - mx), e1 = __expf(S1 - mx), e2 = __expf(S2 - mx);
    float es = e0 + e1 + e2;
    #pragma unroll
    for (int off = 8; off >= 1; off >>= 1) es += __shfl_xor(es, off, 16);
    float rinv = 1.0f / es;
    sP[ l       *4 + h] = e0 * rinv;
    sP[(l + 16) *4 + h] = e1 * rinv;
    sP[(l + 32) *4 + h] = e2 * rinv;

    // T[h', c] = sum_k P[h',k] * KF[k,c]
    float T0 = 0, T1 = 0, T2 = 0, T3 = 0;
    #pragma unroll 8
    for (int k = 0; k < KK; ++k) {
        float kf = skf[k*68 + c];
        float4 p = *(const float4*)&sP[k*4];      // broadcast
        T0 = fmaf(p.x, kf, T0); T1 = fmaf(p.y, kf, T1);
        T2 = fmaf(p.z, kf, T2); T3 = fmaf(p.w, kf, T3);
    }
    sT[0*68 + c] = T0; sT[1*68 + c] = T1; sT[2*68 + c] = T2; sT[3*68 + c] = T3;

    // ctx[c] = bv[c] + sum_cp T[h(c), cp] * Wv[c, cp]
    const float* WvT = tw + TW_WVT;
    float ctx = in_b[128 + c];
    #pragma unroll 8
    for (int cp = 0; cp < 64; ++cp)
        ctx = fmaf(sT[h*68 + cp], WvT[cp*64 + c], ctx);
    sctx[c] = ctx;

    // att[c] = bo[c] + sum_j ctx[j] * Wo[c, j]
    const float* WoT = tw + TW_WOT;
    float att = out_b[c];
    #pragma unroll 8
    for (int j = 0; j < 64; ++j)
        att = fmaf(sctx[j], WoT[j*64 + c], att);
    att_out[(size_t)n*64 + c] = att;
}

// ---------------------------------------------------------------------------
// FFN in-place on d_out: y = att + lin2(relu(lin1(att))). Weights streamed
// from L2 once per 8 queries (register blocking). BN1 stats accumulated.
// ---------------------------------------------------------------------------
__global__ __launch_bounds__(256) void ffn_kernel(
    const float* __restrict__ tw, const float* __restrict__ lin1_b,
    const float* __restrict__ lin2_b, float* __restrict__ att_y,
    float* __restrict__ sum1, float* __restrict__ sumsq1)
{
    __shared__ __align__(16) float satt[4][8*64];
    __shared__ __align__(16) float shid[4][8*256];
    int tid = threadIdx.x, w = tid >> 6, c = tid & 63;
    const float* L1I = tw + TW_L1I;
    const float* L2I = tw + TW_L2I;
    int base = blockIdx.x*32 + w*8;

    #pragma unroll
    for (int q = 0; q < 8; ++q)
        satt[w][q*64 + c] = att_y[(size_t)(base + q)*64 + c];

    float4 lb1 = *(const float4*)&lin1_b[4*c];    // lane c owns hidden f=4c..4c+3
    float acc[8][4];
    #pragma unroll
    for (int q = 0; q < 8; ++q) {
        acc[q][0] = lb1.x; acc[q][1] = lb1.y; acc[q][2] = lb1.z; acc[q][3] = lb1.w;
    }
    for (int j = 0; j < 64; ++j) {
        float4 w4 = *(const float4*)&L1I[j*256 + 4*c];
        #pragma unroll
        for (int q = 0; q < 8; ++q) {
            float a = satt[w][q*64 + j];
            acc[q][0] = fmaf(a, w4.x, acc[q][0]);
            acc[q][1] = fmaf(a, w4.y, acc[q][1]);
            acc[q][2] = fmaf(a, w4.z, acc[q][2]);
            acc[q][3] = fmaf(a, w4.w, acc[q][3]);
        }
    }
    #pragma unroll
    for (int q = 0; q < 8; ++q) {
        float4 hv;
        hv.x = fmaxf(acc[q][0], 0.0f); hv.y = fmaxf(acc[q][1], 0.0f);
        hv.z = fmaxf(acc[q][2], 0.0f); hv.w = fmaxf(acc[q][3], 0.0f);
        *(float4*)&shid[w][q*256 + 4*c] = hv;
    }
    float lb2 = lin2_b[c];
    float y[8];
    #pragma unroll
    for (int q = 0; q < 8; ++q) y[q] = lb2 + satt[w][q*64 + c];   // residual
    for (int f4 = 0; f4 < 64; ++f4) {
        float4 w4 = *(const float4*)&L2I[f4*256 + 4*c];
        #pragma unroll
        for (int q = 0; q < 8; ++q) {
            float4 hv = *(const float4*)&shid[w][q*256 + 4*f4];   // broadcast
            y[q] = fmaf(w4.x, hv.x, y[q]); y[q] = fmaf(w4.y, hv.y, y[q]);
            y[q] = fmaf(w4.z, hv.z, y[q]); y[q] = fmaf(w4.w, hv.w, y[q]);
        }
    }
    float s = 0, ss = 0;
    #pragma unroll
    for (int q = 0; q < 8; ++q) {
        float yv = y[q];
        att_y[(size_t)(base + q)*64 + c] = yv;
        s += yv; ss = fmaf(yv, yv, ss);
    }
    atomicAdd(&sum1[c], s); atomicAdd(&sumsq1[c], ss);
}

// ---------------------------------------------------------------------------
// BN1 (inline stats) + output linear, in-place on d_out; BN2 stats.
// ---------------------------------------------------------------------------
__global__ __launch_bounds__(64) void linout_kernel(
    const float* __restrict__ tw, const float* __restrict__ outl_b,
    const float* __restrict__ norm_g, const float* __restrict__ norm_b,
    const float* __restrict__ sum1, const float* __restrict__ sumsq1,
    float* __restrict__ yz, float* __restrict__ sum2, float* __restrict__ sumsq2)
{
    __shared__ __align__(16) float sOl[4096];
    __shared__ __align__(16) float sxn[64];
    int c = threadIdx.x;
    const float4* Olv = (const float4*)(tw + TW_OLT);
    #pragma unroll
    for (int i = 0; i < 16; ++i)
        ((float4*)sOl)[c + 64*i] = Olv[c + 64*i];
    const float invN = 1.0f / 20000.0f;
    float mu = sum1[c]*invN;
    float var = fmaf(-mu, mu, sumsq1[c]*invN);
    float a1 = norm_g[c] / sqrtf(var + 1e-5f);
    float b1 = fmaf(-mu, a1, norm_b[c]);
    float ob = outl_b[c];
    float s = 0, ss = 0;
    int base = blockIdx.x*32;
    for (int r = 0; r < 32; ++r) {
        int n = base + r;
        float yv = yz[(size_t)n*64 + c];
        sxn[c] = fmaf(yv, a1, b1);                 // single wave: in-order
        float z = ob;
        #pragma unroll 8
        for (int j = 0; j < 64; ++j) z = fmaf(sxn[j], sOl[j*64 + c], z);
        yz[(size_t)n*64 + c] = z;
        s += z; ss = fmaf(z, z, ss);
    }
    atomicAdd(&sum2[c], s); atomicAdd(&sumsq2[c], ss);
}

// ---------------------------------------------------------------------------
// out = relu(bn2(z)) in place; a2/b2 computed inline from sums.
// ---------------------------------------------------------------------------
__global__ void final_kernel(float* __restrict__ z,
    const float* __restrict__ sum2, const float* __restrict__ sumsq2,
    const float* __restrict__ obn_g, const float* __restrict__ obn_b)
{
    int i = blockIdx.x*blockDim.x + threadIdx.x;
    if (i >= N_Q*64/4) return;
    int o4 = (i*4) & 63;
    float4 sm = *(const float4*)&sum2[o4];
    float4 sq = *(const float4*)&sumsq2[o4];
    float4 g  = *(const float4*)&obn_g[o4];
    float4 b  = *(const float4*)&obn_b[o4];
    const float invN = 1.0f / 20000.0f;
    float mux = sm.x*invN, muy = sm.y*invN, muz = sm.z*invN, muw = sm.w*invN;
    float ax = g.x / sqrtf(fmaf(-mux, mux, sq.x*invN) + 1e-5f);
    float ay = g.y / sqrtf(fmaf(-muy, muy, sq.y*invN) + 1e-5f);
    float az = g.z / sqrtf(fmaf(-muz, muz, sq.z*invN) + 1e-5f);
    float aw = g.w / sqrtf(fmaf(-muw, muw, sq.w*invN) + 1e-5f);
    float4 v = ((float4*)z)[i];
    v.x = fmaxf(fmaf(v.x - mux, ax, b.x), 0.0f);
    v.y = fmaxf(fmaf(v.y - muy, ay, b.y), 0.0f);
    v.z = fmaxf(fmaf(v.z - muz, az, b.z), 0.0f);
    v.w = fmaxf(fmaf(v.w - muw, aw, b.w), 0.0f);
    ((float4*)z)[i] = v;
}

extern "C" void kernel_launch(void* const* d_in, const int* in_sizes, int n_in,
                              void* d_out, int out_size, void* d_ws, size_t ws_size,
                              hipStream_t stream)
{
    const float* vfeat  = (const float*)d_in[0];
    const float* vcoord = (const float*)d_in[1];
    const float* qcoord = (const float*)d_in[2];
    const int*   kidx   = (const int*)d_in[3];
    const float* q_w    = (const float*)d_in[4];
    const float* q_b    = (const float*)d_in[5];
    const float* kpos_w = (const float*)d_in[6];
    const float* kpos_b = (const float*)d_in[7];
    const float* in_w   = (const float*)d_in[8];
    const float* in_b   = (const float*)d_in[9];
    const float* out_w  = (const float*)d_in[10];
    const float* out_b  = (const float*)d_in[11];
    const float* lin1_w = (const float*)d_in[12];
    const float* lin1_b = (const float*)d_in[13];
    const float* lin2_w = (const float*)d_in[14];
    const float* lin2_b = (const float*)d_in[15];
    const float* norm_g = (const float*)d_in[16];
    const float* norm_b = (const float*)d_in[17];
    const float* outl_w = (const float*)d_in[18];
    const float* outl_b = (const float*)d_in[19];
    const float* obn_g  = (const float*)d_in[20];
    const float* obn_b  = (const float*)d_in[21];

    float* ws = (float*)d_ws;
    float* tw = ws;
    float* stats = ws + ST_OFF;
    float* sum1 = stats, *sumsq1 = stats + 64, *sum2 = stats + 128, *sumsq2 = stats + 192;
    __hip_bfloat16* M_all = (__hip_bfloat16*)(ws + M_OFF);
    float* xd = (float*)d_out;    // att -> y -> z -> out, all in place

    hipMemsetAsync(stats, 0, 256*sizeof(float), stream);
    prep_weights<<<176, 256, 0, stream>>>(in_w, out_w, lin1_w, lin2_w, outl_w, tw);
    m_kernel<<<625, 256, 0, stream>>>(qcoord, q_w, q_b, in_w, in_b, M_all);
    attn_kernel<<<N_Q, 64, 0, stream>>>(vfeat, vcoord, qcoord, kidx, kpos_w, kpos_b,
                                        in_b, out_b, tw, M_all, xd);
    ffn_kernel<<<625, 256, 0, stream>>>(tw, lin1_b, lin2_b, xd, sum1, sumsq1);
    linout_kernel<<<625, 64, 0, stream>>>(tw, outl_b, norm_g, norm_b, sum1, sumsq1,
                                          xd, sum2, sumsq2);
    final_kernel<<<1250, 256, 0, stream>>>(xd, sum2, sumsq2, obn_g, obn_b);
}